// Round 6
// baseline (63.379 us; speedup 1.0000x reference)
//
#include <hip/hip_runtime.h>
#include <math.h>

#define D_ 512
#define S_ 50
#define M_ 20
#define BN_EPS_ 1e-5f

// ---------- DPP wave-wide sum (64 lanes), result broadcast via readlane(63).
template <int CTRL, int RM>
__device__ __forceinline__ float dpp_step(float x) {
    int t = __builtin_amdgcn_update_dpp(0, __float_as_int(x), CTRL, RM, 0xf, true);
    return x + __int_as_float(t);
}
__device__ __forceinline__ float wave_sum(float x) {
    x = dpp_step<0x111, 0xf>(x);  // row_shr:1
    x = dpp_step<0x112, 0xf>(x);  // row_shr:2
    x = dpp_step<0x114, 0xf>(x);  // row_shr:4
    x = dpp_step<0x118, 0xf>(x);  // row_shr:8
    x = dpp_step<0x142, 0xa>(x);  // row_bcast:15 into rows 1,3
    x = dpp_step<0x143, 0xc>(x);  // row_bcast:31 into rows 2,3 -> lane63 = total
    return __int_as_float(__builtin_amdgcn_readlane(__float_as_int(x), 63));
}

// ---------- setup (6 blocks): normalize 40 text rows; fold BN into classifier
__global__ __launch_bounds__(512) void setup_kernel(
    const float* __restrict__ tf, const float* __restrict__ gamma,
    const float* __restrict__ beta, const float* __restrict__ mean,
    const float* __restrict__ var, const float* __restrict__ wcls,
    const float* __restrict__ bcls, float* __restrict__ ws)
{
    float* tnorm = ws;                 // [40][512]
    float* wf    = ws + 2 * M_ * D_;   // [2][1024]
    float* bf    = wf + 4 * D_;        // [2]
    const int tid  = threadIdx.x;
    const int lane = tid & 63;
    const int wv   = tid >> 6;         // 8 waves

    if (blockIdx.x < 5) {
        const int row = blockIdx.x * 8 + wv;
        const float4* p = (const float4*)(tf + (size_t)row * D_) + lane * 2;
        float4 a = p[0], b = p[1];
        float ss = a.x*a.x + a.y*a.y + a.z*a.z + a.w*a.w
                 + b.x*b.x + b.y*b.y + b.z*b.z + b.w*b.w;
        ss = wave_sum(ss);
        float inv = rsqrtf(ss);
        float4 na = {a.x*inv, a.y*inv, a.z*inv, a.w*inv};
        float4 nb = {b.x*inv, b.y*inv, b.z*inv, b.w*inv};
        float4* q = (float4*)(tnorm + (size_t)row * D_) + lane * 2;
        q[0] = na; q[1] = nb;
    } else {
        __shared__ float r0[8], r1[8];
        float pa = 0.f, pb = 0.f;
        for (int c = tid; c < 2 * D_; c += 512) {
            float s1 = rsqrtf(var[c] + BN_EPS_) * gamma[c];
            float w0 = wcls[c], w1 = wcls[2 * D_ + c];
            wf[c] = w0 * s1;
            wf[2 * D_ + c] = w1 * s1;
            float bmc = beta[c] - mean[c] * s1;
            pa += bmc * w0;
            pb += bmc * w1;
        }
        pa = wave_sum(pa);
        pb = wave_sum(pb);
        if (lane == 0) { r0[wv] = pa; r1[wv] = pb; }
        __syncthreads();
        if (tid == 0) {
            float A = 0.f, Bv = 0.f;
            #pragma unroll
            for (int w = 0; w < 8; ++w) { A += r0[w]; Bv += r1[w]; }
            bf[0] = bcls[0] + A;
            bf[1] = bcls[1] + Bv;
        }
    }
}

// ---------- main: four waves per b; 2 barriers; redundant per-wave tbar ----
__global__ __launch_bounds__(256, 4) void main_kernel(
    const float* __restrict__ img, const int* __restrict__ rad,
    const int* __restrict__ vm, const float* __restrict__ ws,
    float* __restrict__ out)
{
    const float* tnorm = ws;
    const float* wf    = ws + 2 * M_ * D_;
    const float* bf    = wf + 4 * D_;
    const int tid  = threadIdx.x;
    const int lane = tid & 63;
    const int wv   = tid >> 6;          // 0..3
    const int b    = blockIdx.x;

    // per-wave partial slots; [w][j*64+lane] -> lane-consecutive b32 (2-way = free)
    __shared__ float accS[4][D_];
    __shared__ float accP[4][D_];
    __shared__ float accT[4][D_];

    // ---- tiny per-b loads
    int vmv  = (lane < S_) ? vm[(size_t)b * S_ + lane] : 0;
    int radv = (lane < M_) ? rad[(size_t)b * M_ + lane] : 0;
    unsigned long long bal = __ballot(lane < S_ && vmv == 1);
    float cnt_inv = 1.0f / fmaxf((float)__popcll(bal), 1.0f);

    // this wave's image rows: s % 4 == wv
    unsigned long long wb = bal & (0x1111111111111111ULL << wv);
    const float* imgb = img + (size_t)b * S_ * D_;

    // ---- 4-deep prefetch issued before tbar (overlaps HBM latency)
    int sA = -1, sB = -1, sC = -1, sD = -1;
    float4 A0{}, A1{}, B0{}, B1{}, C0{}, C1{}, E0{}, E1{};
    if (wb) {
        sA = __ffsll(wb) - 1; wb &= wb - 1;
        const float4* p = (const float4*)(imgb + (size_t)sA * D_) + lane * 2;
        A0 = p[0]; A1 = p[1];
    }
    if (wb) {
        sB = __ffsll(wb) - 1; wb &= wb - 1;
        const float4* p = (const float4*)(imgb + (size_t)sB * D_) + lane * 2;
        B0 = p[0]; B1 = p[1];
    }
    if (wb) {
        sC = __ffsll(wb) - 1; wb &= wb - 1;
        const float4* p = (const float4*)(imgb + (size_t)sC * D_) + lane * 2;
        C0 = p[0]; C1 = p[1];
    }
    if (wb) {
        sD = __ffsll(wb) - 1; wb &= wb - 1;
        const float4* p = (const float4*)(imgb + (size_t)sD * D_) + lane * 2;
        E0 = p[0]; E1 = p[1];
    }

    // ---- tbar: redundant per wave (all 20 rows; L2-resident, overlaps prefetch)
    float tb[8] = {0,0,0,0,0,0,0,0};
    #pragma unroll
    for (int m = 0; m < M_; ++m) {
        int rm = __builtin_amdgcn_readlane(radv, m);
        const float4* p = (const float4*)(tnorm + (size_t)(2 * m + rm) * D_) + lane * 2;
        float4 x = p[0], y = p[1];
        tb[0] += x.x; tb[1] += x.y; tb[2] += x.z; tb[3] += x.w;
        tb[4] += y.x; tb[5] += y.y; tb[6] += y.z; tb[7] += y.w;
    }
    #pragma unroll
    for (int j = 0; j < 8; ++j) tb[j] *= (1.0f / (float)M_);

    // ---- image pass over this wave's rows, DPP reductions
    float isum[8]  = {0,0,0,0,0,0,0,0};
    float ipool[8] = {0,0,0,0,0,0,0,0};
    while (sA >= 0) {
        float v[8] = {A0.x, A0.y, A0.z, A0.w, A1.x, A1.y, A1.z, A1.w};
        float ss = 0.f, ar = 0.f;
        #pragma unroll
        for (int j = 0; j < 8; ++j) { ss += v[j] * v[j]; ar += tb[j] * v[j]; }
        ss = wave_sum(ss);
        ar = wave_sum(ar);
        float inv = rsqrtf(ss);
        float w2  = ar * inv * inv;   // attn_image * inv, folded
        #pragma unroll
        for (int j = 0; j < 8; ++j) {
            isum[j]  += v[j] * inv;
            ipool[j] += v[j] * w2;
        }
        sA = sB; A0 = B0; A1 = B1;
        sB = sC; B0 = C0; B1 = C1;
        sC = sD; C0 = E0; C1 = E1;
        sD = -1;
        if (wb) {
            sD = __ffsll(wb) - 1; wb &= wb - 1;
            const float4* p = (const float4*)(imgb + (size_t)sD * D_) + lane * 2;
            E0 = p[0]; E1 = p[1];
        }
    }
    #pragma unroll
    for (int j = 0; j < 8; ++j) {
        accS[wv][j * 64 + lane] = isum[j];
        accP[wv][j * 64 + lane] = ipool[j];
    }
    __syncthreads();  // 1

    // combined imgsum, needed by every wave for the text dots
    float as8[8];
    #pragma unroll
    for (int j = 0; j < 8; ++j)
        as8[j] = accS[0][j * 64 + lane] + accS[1][j * 64 + lane]
               + accS[2][j * 64 + lane] + accS[3][j * 64 + lane];

    // ---- fused attn_text + txt_pool partial over m = wv + 4k
    float tpp[8] = {0,0,0,0,0,0,0,0};
    #pragma unroll
    for (int k = 0; k < M_ / 4; ++k) {
        int m  = wv + 4 * k;
        int rm = __builtin_amdgcn_readlane(radv, m);
        const float4* p = (const float4*)(tnorm + (size_t)(2 * m + rm) * D_) + lane * 2;
        float4 x = p[0], y = p[1];
        float tv[8] = {x.x, x.y, x.z, x.w, y.x, y.y, y.z, y.w};
        float d = 0.f;
        #pragma unroll
        for (int j = 0; j < 8; ++j) d += tv[j] * as8[j];
        float a = wave_sum(d) * cnt_inv;      // attn_text[m]
        #pragma unroll
        for (int j = 0; j < 8; ++j) tpp[j] += a * tv[j];
    }
    #pragma unroll
    for (int j = 0; j < 8; ++j) accT[wv][j * 64 + lane] = tpp[j];
    __syncthreads();  // 2

    // ---- tail: wave 0 only
    if (wv != 0) return;

    // issue weight loads first so latency overlaps the combines below
    const float4* w00 = (const float4*)(wf)          + lane * 2;  // out0, img half
    const float4* w01 = (const float4*)(wf + D_)     + lane * 2;  // out0, txt half
    const float4* w10 = (const float4*)(wf + 2 * D_) + lane * 2;  // out1, img half
    const float4* w11 = (const float4*)(wf + 3 * D_) + lane * 2;  // out1, txt half
    float4 a0 = w00[0], a1 = w00[1], b0 = w01[0], b1 = w01[1];
    float4 c0 = w10[0], c1 = w10[1], d0 = w11[0], d1 = w11[1];

    float ap8[8], tp8[8];
    float ipl = 0.f, tpl = 0.f;
    #pragma unroll
    for (int j = 0; j < 8; ++j) {
        ap8[j] = accP[0][j * 64 + lane] + accP[1][j * 64 + lane]
               + accP[2][j * 64 + lane] + accP[3][j * 64 + lane];
        tp8[j] = accT[0][j * 64 + lane] + accT[1][j * 64 + lane]
               + accT[2][j * 64 + lane] + accT[3][j * 64 + lane];
        ipl += ap8[j] * ap8[j];
        tpl += tp8[j] * tp8[j];
    }
    float inv_ip = rsqrtf(wave_sum(ipl));
    float inv_tp = rsqrtf(wave_sum(tpl));

    float wA[8] = {a0.x,a0.y,a0.z,a0.w,a1.x,a1.y,a1.z,a1.w};
    float wB[8] = {b0.x,b0.y,b0.z,b0.w,b1.x,b1.y,b1.z,b1.w};
    float wC[8] = {c0.x,c0.y,c0.z,c0.w,c1.x,c1.y,c1.z,c1.w};
    float wD[8] = {d0.x,d0.y,d0.z,d0.w,d1.x,d1.y,d1.z,d1.w};
    float o0 = 0.f, o1 = 0.f;
    #pragma unroll
    for (int j = 0; j < 8; ++j) {
        float h1 = fmaxf(ap8[j] * inv_ip, 0.f);
        float h2 = fmaxf(tp8[j] * inv_tp, 0.f);
        o0 += h1 * wA[j] + h2 * wB[j];
        o1 += h1 * wC[j] + h2 * wD[j];
    }
    o0 = wave_sum(o0);
    o1 = wave_sum(o1);
    if (lane == 0) {
        float2 r = {o0 + bf[0], o1 + bf[1]};
        *(float2*)(out + (size_t)b * 2) = r;
    }
}

extern "C" void kernel_launch(void* const* d_in, const int* in_sizes, int n_in,
                              void* d_out, int out_size, void* d_ws, size_t ws_size,
                              hipStream_t stream) {
    const float* img   = (const float*)d_in[0];
    const float* tf    = (const float*)d_in[1];
    const int*   rad   = (const int*)d_in[2];
    const int*   vmsk  = (const int*)d_in[3];
    const float* gamma = (const float*)d_in[4];
    const float* beta  = (const float*)d_in[5];
    const float* mean  = (const float*)d_in[6];
    const float* var   = (const float*)d_in[7];
    const float* wcls  = (const float*)d_in[8];
    const float* bcls  = (const float*)d_in[9];
    float* out = (float*)d_out;
    float* ws  = (float*)d_ws;

    const int B = in_sizes[0] / (S_ * D_);  // 4096

    setup_kernel<<<6, 512, 0, stream>>>(tf, gamma, beta, mean, var, wcls, bcls, ws);
    main_kernel<<<B, 256, 0, stream>>>(img, rad, vmsk, ws, out);
}

// Round 7
// 49.165 us; speedup vs baseline: 1.2891x; 1.2891x over previous
//
#include <hip/hip_runtime.h>
#include <math.h>

#define D_ 512
#define S_ 50
#define M_ 20
#define BN_EPS_ 1e-5f

// ---------- DPP wave-wide sum (64 lanes), result broadcast via readlane(63).
template <int CTRL, int RM>
__device__ __forceinline__ float dpp_step(float x) {
    int t = __builtin_amdgcn_update_dpp(0, __float_as_int(x), CTRL, RM, 0xf, true);
    return x + __int_as_float(t);
}
__device__ __forceinline__ float wave_sum(float x) {
    x = dpp_step<0x111, 0xf>(x);  // row_shr:1
    x = dpp_step<0x112, 0xf>(x);  // row_shr:2
    x = dpp_step<0x114, 0xf>(x);  // row_shr:4
    x = dpp_step<0x118, 0xf>(x);  // row_shr:8
    x = dpp_step<0x142, 0xa>(x);  // row_bcast:15 into rows 1,3
    x = dpp_step<0x143, 0xc>(x);  // row_bcast:31 into rows 2,3 -> lane63 = total
    return __int_as_float(__builtin_amdgcn_readlane(__float_as_int(x), 63));
}

// ---------- setup (6 blocks): normalize 40 text rows; fold BN into classifier
__global__ __launch_bounds__(512) void setup_kernel(
    const float* __restrict__ tf, const float* __restrict__ gamma,
    const float* __restrict__ beta, const float* __restrict__ mean,
    const float* __restrict__ var, const float* __restrict__ wcls,
    const float* __restrict__ bcls, float* __restrict__ ws)
{
    float* tnorm = ws;                 // [40][512]
    float* wf    = ws + 2 * M_ * D_;   // [2][1024]
    float* bf    = wf + 4 * D_;        // [2]
    const int tid  = threadIdx.x;
    const int lane = tid & 63;
    const int wv   = tid >> 6;         // 8 waves

    if (blockIdx.x < 5) {
        const int row = blockIdx.x * 8 + wv;
        const float4* p = (const float4*)(tf + (size_t)row * D_) + lane * 2;
        float4 a = p[0], b = p[1];
        float ss = a.x*a.x + a.y*a.y + a.z*a.z + a.w*a.w
                 + b.x*b.x + b.y*b.y + b.z*b.z + b.w*b.w;
        ss = wave_sum(ss);
        float inv = rsqrtf(ss);
        float4 na = {a.x*inv, a.y*inv, a.z*inv, a.w*inv};
        float4 nb = {b.x*inv, b.y*inv, b.z*inv, b.w*inv};
        float4* q = (float4*)(tnorm + (size_t)row * D_) + lane * 2;
        q[0] = na; q[1] = nb;
    } else {
        __shared__ float r0[8], r1[8];
        float pa = 0.f, pb = 0.f;
        for (int c = tid; c < 2 * D_; c += 512) {
            float s1 = rsqrtf(var[c] + BN_EPS_) * gamma[c];
            float w0 = wcls[c], w1 = wcls[2 * D_ + c];
            wf[c] = w0 * s1;
            wf[2 * D_ + c] = w1 * s1;
            float bmc = beta[c] - mean[c] * s1;
            pa += bmc * w0;
            pb += bmc * w1;
        }
        pa = wave_sum(pa);
        pb = wave_sum(pb);
        if (lane == 0) { r0[wv] = pa; r1[wv] = pb; }
        __syncthreads();
        if (tid == 0) {
            float A = 0.f, Bv = 0.f;
            #pragma unroll
            for (int w = 0; w < 8; ++w) { A += r0[w]; Bv += r1[w]; }
            bf[0] = bcls[0] + A;
            bf[1] = bcls[1] + Bv;
        }
    }
}

// ---------- main: four waves per b (round-5 structure); 24 KB LDS ----------
__global__ __launch_bounds__(256, 5) void main_kernel(
    const float* __restrict__ img, const int* __restrict__ rad,
    const int* __restrict__ vm, const float* __restrict__ ws,
    float* __restrict__ out)
{
    const float* tnorm = ws;
    const float* wf    = ws + 2 * M_ * D_;
    const float* bf    = wf + 4 * D_;
    const int tid  = threadIdx.x;
    const int lane = tid & 63;
    const int wv   = tid >> 6;          // 0..3
    const int b    = blockIdx.x;

    // per-wave partial slots; [w][j*64+lane] -> lane-consecutive b32 (2-way = free)
    // shTA: tbar partials first, REUSED as accT after barrier 2 (all tbar reads
    // complete before barrier 2; accT writes happen after it).
    __shared__ float shTA[4][D_];
    __shared__ float accS[4][D_];
    __shared__ float accP[4][D_];

    // ---- tiny per-b loads
    int vmv  = (lane < S_) ? vm[(size_t)b * S_ + lane] : 0;
    int radv = (lane < M_) ? rad[(size_t)b * M_ + lane] : 0;
    unsigned long long bal = __ballot(lane < S_ && vmv == 1);
    float cnt_inv = 1.0f / fmaxf((float)__popcll(bal), 1.0f);

    // this wave's image rows: s % 4 == wv
    unsigned long long wb = bal & (0x1111111111111111ULL << wv);
    const float* imgb = img + (size_t)b * S_ * D_;

    // ---- 3-deep prefetch, issued before the tbar phase (overlaps HBM latency)
    int sA = -1, sB = -1, sC = -1;
    float4 A0{}, A1{}, B0{}, B1{}, C0{}, C1{};
    if (wb) {
        sA = __ffsll(wb) - 1; wb &= wb - 1;
        const float4* p = (const float4*)(imgb + (size_t)sA * D_) + lane * 2;
        A0 = p[0]; A1 = p[1];
    }
    if (wb) {
        sB = __ffsll(wb) - 1; wb &= wb - 1;
        const float4* p = (const float4*)(imgb + (size_t)sB * D_) + lane * 2;
        B0 = p[0]; B1 = p[1];
    }
    if (wb) {
        sC = __ffsll(wb) - 1; wb &= wb - 1;
        const float4* p = (const float4*)(imgb + (size_t)sC * D_) + lane * 2;
        C0 = p[0]; C1 = p[1];
    }

    // ---- tbar partial over m = wv + 4k (5 rows per wave)
    float tbp[8] = {0,0,0,0,0,0,0,0};
    #pragma unroll
    for (int k = 0; k < M_ / 4; ++k) {
        int m  = wv + 4 * k;
        int rm = __builtin_amdgcn_readlane(radv, m);   // uniform lane idx (SGPR)
        const float4* p = (const float4*)(tnorm + (size_t)(2 * m + rm) * D_) + lane * 2;
        float4 x = p[0], y = p[1];
        tbp[0] += x.x; tbp[1] += x.y; tbp[2] += x.z; tbp[3] += x.w;
        tbp[4] += y.x; tbp[5] += y.y; tbp[6] += y.z; tbp[7] += y.w;
    }
    #pragma unroll
    for (int j = 0; j < 8; ++j) shTA[wv][j * 64 + lane] = tbp[j];
    __syncthreads();  // 1

    float tb[8];
    #pragma unroll
    for (int j = 0; j < 8; ++j) {
        float s = shTA[0][j * 64 + lane] + shTA[1][j * 64 + lane]
                + shTA[2][j * 64 + lane] + shTA[3][j * 64 + lane];
        tb[j] = s * (1.0f / (float)M_);
    }

    // ---- image pass over this wave's rows (~6), DPP reductions
    float isum[8]  = {0,0,0,0,0,0,0,0};
    float ipool[8] = {0,0,0,0,0,0,0,0};
    while (sA >= 0) {
        float v[8] = {A0.x, A0.y, A0.z, A0.w, A1.x, A1.y, A1.z, A1.w};
        float ss = 0.f, ar = 0.f;
        #pragma unroll
        for (int j = 0; j < 8; ++j) { ss += v[j] * v[j]; ar += tb[j] * v[j]; }
        ss = wave_sum(ss);
        ar = wave_sum(ar);
        float inv = rsqrtf(ss);
        float w2  = ar * inv * inv;   // attn_image * inv, folded
        #pragma unroll
        for (int j = 0; j < 8; ++j) {
            isum[j]  += v[j] * inv;
            ipool[j] += v[j] * w2;
        }
        sA = sB; A0 = B0; A1 = B1;
        sB = sC; B0 = C0; B1 = C1;
        sC = -1;
        if (wb) {
            sC = __ffsll(wb) - 1; wb &= wb - 1;
            const float4* p = (const float4*)(imgb + (size_t)sC * D_) + lane * 2;
            C0 = p[0]; C1 = p[1];
        }
    }
    #pragma unroll
    for (int j = 0; j < 8; ++j) {
        accS[wv][j * 64 + lane] = isum[j];
        accP[wv][j * 64 + lane] = ipool[j];
    }
    __syncthreads();  // 2

    // combined imgsum, needed by every wave for the text dots
    float as8[8];
    #pragma unroll
    for (int j = 0; j < 8; ++j)
        as8[j] = accS[0][j * 64 + lane] + accS[1][j * 64 + lane]
               + accS[2][j * 64 + lane] + accS[3][j * 64 + lane];

    // ---- fused attn_text + txt_pool partial over m = wv + 4k
    float tpp[8] = {0,0,0,0,0,0,0,0};
    #pragma unroll
    for (int k = 0; k < M_ / 4; ++k) {
        int m  = wv + 4 * k;
        int rm = __builtin_amdgcn_readlane(radv, m);
        const float4* p = (const float4*)(tnorm + (size_t)(2 * m + rm) * D_) + lane * 2;
        float4 x = p[0], y = p[1];
        float tv[8] = {x.x, x.y, x.z, x.w, y.x, y.y, y.z, y.w};
        float d = 0.f;
        #pragma unroll
        for (int j = 0; j < 8; ++j) d += tv[j] * as8[j];
        float a = wave_sum(d) * cnt_inv;      // attn_text[m]
        #pragma unroll
        for (int j = 0; j < 8; ++j) tpp[j] += a * tv[j];
    }
    #pragma unroll
    for (int j = 0; j < 8; ++j) shTA[wv][j * 64 + lane] = tpp[j];  // accT (reuse)
    __syncthreads();  // 3

    // ---- tail: wave 0 only
    if (wv != 0) return;

    // issue weight loads first so latency overlaps the combines below
    const float4* w00 = (const float4*)(wf)          + lane * 2;  // out0, img half
    const float4* w01 = (const float4*)(wf + D_)     + lane * 2;  // out0, txt half
    const float4* w10 = (const float4*)(wf + 2 * D_) + lane * 2;  // out1, img half
    const float4* w11 = (const float4*)(wf + 3 * D_) + lane * 2;  // out1, txt half
    float4 a0 = w00[0], a1 = w00[1], b0 = w01[0], b1 = w01[1];
    float4 c0 = w10[0], c1 = w10[1], d0 = w11[0], d1 = w11[1];

    float ap8[8], tp8[8];
    float ipl = 0.f, tpl = 0.f;
    #pragma unroll
    for (int j = 0; j < 8; ++j) {
        ap8[j] = accP[0][j * 64 + lane] + accP[1][j * 64 + lane]
               + accP[2][j * 64 + lane] + accP[3][j * 64 + lane];
        tp8[j] = shTA[0][j * 64 + lane] + shTA[1][j * 64 + lane]
               + shTA[2][j * 64 + lane] + shTA[3][j * 64 + lane];
        ipl += ap8[j] * ap8[j];
        tpl += tp8[j] * tp8[j];
    }
    float inv_ip = rsqrtf(wave_sum(ipl));
    float inv_tp = rsqrtf(wave_sum(tpl));

    float wA[8] = {a0.x,a0.y,a0.z,a0.w,a1.x,a1.y,a1.z,a1.w};
    float wB[8] = {b0.x,b0.y,b0.z,b0.w,b1.x,b1.y,b1.z,b1.w};
    float wC[8] = {c0.x,c0.y,c0.z,c0.w,c1.x,c1.y,c1.z,c1.w};
    float wD[8] = {d0.x,d0.y,d0.z,d0.w,d1.x,d1.y,d1.z,d1.w};
    float o0 = 0.f, o1 = 0.f;
    #pragma unroll
    for (int j = 0; j < 8; ++j) {
        float h1 = fmaxf(ap8[j] * inv_ip, 0.f);
        float h2 = fmaxf(tp8[j] * inv_tp, 0.f);
        o0 += h1 * wA[j] + h2 * wB[j];
        o1 += h1 * wC[j] + h2 * wD[j];
    }
    o0 = wave_sum(o0);
    o1 = wave_sum(o1);
    if (lane == 0) {
        float2 r = {o0 + bf[0], o1 + bf[1]};
        *(float2*)(out + (size_t)b * 2) = r;
    }
}

extern "C" void kernel_launch(void* const* d_in, const int* in_sizes, int n_in,
                              void* d_out, int out_size, void* d_ws, size_t ws_size,
                              hipStream_t stream) {
    const float* img   = (const float*)d_in[0];
    const float* tf    = (const float*)d_in[1];
    const int*   rad   = (const int*)d_in[2];
    const int*   vmsk  = (const int*)d_in[3];
    const float* gamma = (const float*)d_in[4];
    const float* beta  = (const float*)d_in[5];
    const float* mean  = (const float*)d_in[6];
    const float* var   = (const float*)d_in[7];
    const float* wcls  = (const float*)d_in[8];
    const float* bcls  = (const float*)d_in[9];
    float* out = (float*)d_out;
    float* ws  = (float*)d_ws;

    const int B = in_sizes[0] / (S_ * D_);  // 4096

    setup_kernel<<<6, 512, 0, stream>>>(tf, gamma, beta, mean, var, wcls, bcls, ws);
    main_kernel<<<B, 256, 0, stream>>>(img, rad, vmsk, ws, out);
}